// Round 1
// baseline (607.152 us; speedup 1.0000x reference)
//
#include <hip/hip_runtime.h>
#include <math.h>

// InfoNCE loss: a,p,n are [B, D] f32. Per row:
//   pos = dot(a,p)/(max(|a|,eps)*max(|p|,eps))
//   neg = dot(a,n)/(max(|a|,eps)*max(|n|,eps))
//   loss_i = logsumexp(pos/T, neg/T) - pos/T  = softplus((neg-pos)/T)
// out = mean(loss_i)
//
// R1 theory: previous version (648 µs) was ~20% of achievable HBM BW on a
// purely-streaming 805 MB problem (roofline ~128 µs). Restructure for
// latency: 16-lane row teams (4 rows/wave in flight, 24 loads outstanding
// vs 6), 4-stage reduce shared by 4 rows (5 shuffles/row vs 30),
// nontemporal loads, softplus-form loss tail.

typedef float f32x4 __attribute__((ext_vector_type(4)));

#define D_DIM 512
#define TEMP_INV (1.0f / 1.5f)
#define EPS_N 1e-12f

constexpr int BLOCKS = 2048;
constexpr int TPB = 256;
constexpr int WAVES_PER_BLOCK = TPB / 64;               // 4
constexpr int TOTAL_WAVES = BLOCKS * WAVES_PER_BLOCK;   // 8192
constexpr int RPG = 4;  // rows per wave-iteration (one per 16-lane team)

__global__ __launch_bounds__(TPB, 4) void infonce_partial(
    const float* __restrict__ a, const float* __restrict__ p,
    const float* __restrict__ n, float* __restrict__ partial, int B) {
  const int lane = threadIdx.x & 63;
  const int wave_in_block = threadIdx.x >> 6;
  const int wave = blockIdx.x * WAVES_PER_BLOCK + wave_in_block;
  const int sub = lane >> 4;   // which of the 4 rows this lane works on
  const int t = lane & 15;     // slice index within the row's 16-lane team

  float loss_acc = 0.0f;

  for (int g = wave; g * RPG < B; g += TOTAL_WAVES) {
    const int row = g * RPG + sub;
    float aa = 0.f, pp = 0.f, nn = 0.f, ap = 0.f, an = 0.f;
    if (row < B) {
      const f32x4* a4 = (const f32x4*)(a + (size_t)row * D_DIM);
      const f32x4* p4 = (const f32x4*)(p + (size_t)row * D_DIM);
      const f32x4* n4 = (const f32x4*)(n + (size_t)row * D_DIM);
      // 512 floats / 16 lanes = 32 floats = 8 float4 per lane per array.
#pragma unroll
      for (int j = 0; j < 8; ++j) {
        const int idx = t + 16 * j;
        f32x4 av = __builtin_nontemporal_load(&a4[idx]);
        f32x4 pv = __builtin_nontemporal_load(&p4[idx]);
        f32x4 nv = __builtin_nontemporal_load(&n4[idx]);
        aa = fmaf(av.x, av.x, fmaf(av.y, av.y, fmaf(av.z, av.z, fmaf(av.w, av.w, aa))));
        pp = fmaf(pv.x, pv.x, fmaf(pv.y, pv.y, fmaf(pv.z, pv.z, fmaf(pv.w, pv.w, pp))));
        nn = fmaf(nv.x, nv.x, fmaf(nv.y, nv.y, fmaf(nv.z, nv.z, fmaf(nv.w, nv.w, nn))));
        ap = fmaf(av.x, pv.x, fmaf(av.y, pv.y, fmaf(av.z, pv.z, fmaf(av.w, pv.w, ap))));
        an = fmaf(av.x, nv.x, fmaf(av.y, nv.y, fmaf(av.z, nv.z, fmaf(av.w, nv.w, an))));
      }
    }

    // Butterfly across the 16 lanes of each row-team (xor offs 8,4,2,1 stay
    // inside the team). Executed by ALL lanes (shuffles need full exec mask);
    // OOB rows contribute zeros and are masked out of the loss below.
#pragma unroll
    for (int off = 8; off > 0; off >>= 1) {
      aa += __shfl_xor(aa, off);
      pp += __shfl_xor(pp, off);
      nn += __shfl_xor(nn, off);
      ap += __shfl_xor(ap, off);
      an += __shfl_xor(an, off);
    }

    if (row < B && t == 0) {
      const float na = fmaxf(sqrtf(aa), EPS_N);
      const float np = fmaxf(sqrtf(pp), EPS_N);
      const float nv2 = fmaxf(sqrtf(nn), EPS_N);
      const float l0 = (ap / (na * np)) * TEMP_INV;
      const float l1 = (an / (na * nv2)) * TEMP_INV;
      const float d = l1 - l0;
      // lse(l0,l1) - l0 = softplus(d), computed stably.
      loss_acc += fmaxf(d, 0.0f) + log1pf(expf(-fabsf(d)));
    }
  }

  // Sum the 4 team leaders (lanes 0,16,32,48; other lanes hold 0).
  loss_acc += __shfl_xor(loss_acc, 16);
  loss_acc += __shfl_xor(loss_acc, 32);

  __shared__ float sh[WAVES_PER_BLOCK];
  if (lane == 0) sh[wave_in_block] = loss_acc;
  __syncthreads();
  if (threadIdx.x == 0) {
    float s = 0.f;
#pragma unroll
    for (int i = 0; i < WAVES_PER_BLOCK; ++i) s += sh[i];
    partial[blockIdx.x] = s;
  }
}

__global__ __launch_bounds__(256) void reduce_partials(
    const float* __restrict__ partial, float* __restrict__ out, int B) {
  __shared__ float sh[256];
  float s = 0.f;
  for (int i = threadIdx.x; i < BLOCKS; i += 256) s += partial[i];
  sh[threadIdx.x] = s;
  __syncthreads();
  for (int off = 128; off > 0; off >>= 1) {
    if (threadIdx.x < off) sh[threadIdx.x] += sh[threadIdx.x + off];
    __syncthreads();
  }
  if (threadIdx.x == 0) out[0] = sh[0] / (float)B;
}

extern "C" void kernel_launch(void* const* d_in, const int* in_sizes, int n_in,
                              void* d_out, int out_size, void* d_ws, size_t ws_size,
                              hipStream_t stream) {
  const float* a = (const float*)d_in[0];   // anchors
  const float* p = (const float*)d_in[1];   // positives
  const float* n = (const float*)d_in[2];   // negatives
  float* partial = (float*)d_ws;            // BLOCKS floats = 8 KB
  float* out = (float*)d_out;
  const int B = in_sizes[0] / D_DIM;

  infonce_partial<<<BLOCKS, TPB, 0, stream>>>(a, p, n, partial, B);
  reduce_partials<<<1, 256, 0, stream>>>(partial, out, B);
}